// Round 10
// baseline (515.038 us; speedup 1.0000x reference)
//
#include <hip/hip_runtime.h>
#include <hip/hip_bf16.h>
#include <cstdint>

#define NV 8192
#define FIN 512
#define FOUT 256
#define KS 8
#define ALPHA_LRELU 0.2f

using bf16x8 = __attribute__((ext_vector_type(8))) short;
using f32x4  = __attribute__((ext_vector_type(4))) float;

static __device__ __forceinline__ float b2f(ushort u) {
  union { uint32_t u32; float f; } v; v.u32 = ((uint32_t)u) << 16; return v.f;
}
static __device__ __forceinline__ ushort f2b(float f) {
  union { float f; uint32_t u; } v; v.f = f;
  uint32_t r = (v.u + 0x7fffu + ((v.u >> 16) & 1u)) >> 16;
  return (ushort)r;
}
static __device__ __forceinline__ uint32_t pk2(float a, float b) {
  return (uint32_t)f2b(a) | ((uint32_t)f2b(b) << 16);
}
// swizzled element index of an 8-elem (16B) chunk; tile row stride 64 elems (128B)
static __device__ __forceinline__ int swz(int row, int kchunk) {
  return (row << 6) + (((kchunk ^ (row & 7)) & 7) << 3);
}
// direct global->LDS, 16B per lane (dest = wave-uniform base + lane*16)
static __device__ __forceinline__ void gl_lds16(const ushort* g, ushort* l) {
  __builtin_amdgcn_global_load_lds(
      (const __attribute__((address_space(1))) uint32_t*)(uintptr_t)g,
      (__attribute__((address_space(3))) uint32_t*)(uint32_t)(uintptr_t)l,
      16, 0, 0);
}
#define SBAR0() __builtin_amdgcn_sched_barrier(0)

// ---------------- prep: W f32 -> WT bf16 (transposed) + zero f1/f2 ----------------
__global__ void k_prep_w(const float* __restrict__ W, ushort* __restrict__ WT,
                         float* __restrict__ f1z) {
  int t = blockIdx.x * 256 + threadIdx.x;
  int n = t >> 9, k = t & 511;
  WT[(size_t)n * FIN + k] = f2b(W[(size_t)k * FOUT + n]);
  if (t < 2 * NV) f1z[t] = 0.f;          // f1 and f2 are contiguous
}

// ---------------- kernel 1: WhT[c][i] = (h@W)^T bf16, + f1/f2 partials ----------------
// BM=64, BN=64, BK=64; 256 thr (4 waves, 2x2); grid (128, 4); pipelined 2-phase dbuf.
__global__ __launch_bounds__(256, 2) void k_gemm1(
    const float* __restrict__ h, const ushort* __restrict__ WT,
    const float* __restrict__ a,
    ushort* __restrict__ WhT, float* __restrict__ f1, float* __restrict__ f2) {
  __shared__ __align__(16) ushort As[2][64 * 64];
  __shared__ __align__(16) ushort Ws[2][64 * 64];
  const int t = threadIdx.x;
  const int lane = t & 63;
  const int w = t >> 6;
  const int wm = w >> 1, wn = w & 1;
  const int i0 = blockIdx.x * 64;
  const int n0 = blockIdx.y * 64;
  const int srow = t & 63, sseg = t >> 6;
  const int NT1 = FIN / 64;                        // 8 k-tiles

  f32x4 acc[2][2] = {};
  uint4 hA0, hA1, wA0, wA1;
  uint4 hB0, hB1, wB0, wB1;

  auto loadregs = [&](int kt, uint4& h0, uint4& h1, uint4& w0, uint4& w1) {
    const float4* gA = (const float4*)(h + (size_t)(i0 + srow) * FIN + kt * 64 + sseg * 16);
    float4 v0 = gA[0], v1 = gA[1], v2 = gA[2], v3 = gA[3];
    h0.x = pk2(v0.x, v0.y); h0.y = pk2(v0.z, v0.w);
    h0.z = pk2(v1.x, v1.y); h0.w = pk2(v1.z, v1.w);
    h1.x = pk2(v2.x, v2.y); h1.y = pk2(v2.z, v2.w);
    h1.z = pk2(v3.x, v3.y); h1.w = pk2(v3.z, v3.w);
    const uint4* gB = (const uint4*)(WT + (size_t)(n0 + srow) * FIN + kt * 64 + sseg * 16);
    w0 = gB[0]; w1 = gB[1];
  };
  auto writeLds = [&](const uint4& h0, const uint4& h1, const uint4& w0, const uint4& w1,
                      int buf) {
    *(uint4*)&As[buf][swz(srow, sseg * 2 + 0)] = h0;
    *(uint4*)&As[buf][swz(srow, sseg * 2 + 1)] = h1;
    *(uint4*)&Ws[buf][swz(srow, sseg * 2 + 0)] = w0;
    *(uint4*)&Ws[buf][swz(srow, sseg * 2 + 1)] = w1;
  };
  auto mfma1 = [&](int buf) {
#pragma unroll
    for (int kk = 0; kk < 2; ++kk) {
      const int kc = kk * 4 + (lane >> 4);
      bf16x8 af[2], bfv[2];
#pragma unroll
      for (int fi = 0; fi < 2; ++fi)
        af[fi] = *(const bf16x8*)&As[buf][swz(wm * 32 + fi * 16 + (lane & 15), kc)];
#pragma unroll
      for (int fj = 0; fj < 2; ++fj)
        bfv[fj] = *(const bf16x8*)&Ws[buf][swz(wn * 32 + fj * 16 + (lane & 15), kc)];
#pragma unroll
      for (int fi = 0; fi < 2; ++fi)
#pragma unroll
        for (int fj = 0; fj < 2; ++fj)
          acc[fi][fj] = __builtin_amdgcn_mfma_f32_16x16x32_bf16(af[fi], bfv[fj], acc[fi][fj], 0, 0, 0);
    }
  };

  loadregs(0, hA0, hA1, wA0, wA1);
  loadregs(1, hB0, hB1, wB0, wB1);
  writeLds(hA0, hA1, wA0, wA1, 0);
  __syncthreads();

  for (int kt = 0; kt + 2 < NT1; kt += 2) {
    loadregs(kt + 2, hA0, hA1, wA0, wA1);
    SBAR0();
    mfma1(0);
    writeLds(hB0, hB1, wB0, wB1, 1);
    __syncthreads();
    loadregs(kt + 3, hB0, hB1, wB0, wB1);
    SBAR0();
    mfma1(1);
    writeLds(hA0, hA1, wA0, wA1, 0);
    __syncthreads();
  }
  mfma1(0);
  writeLds(hB0, hB1, wB0, wB1, 1);
  __syncthreads();
  mfma1(1);

  float p1[2][4] = {}, p2[2][4] = {};
#pragma unroll
  for (int fi = 0; fi < 2; ++fi) {
    const int row0 = i0 + wm * 32 + fi * 16 + ((lane >> 4) << 2);
#pragma unroll
    for (int fj = 0; fj < 2; ++fj) {
      const int col = n0 + wn * 32 + fj * 16 + (lane & 15);
      const float a1c = a[col], a2c = a[FOUT + col];
      ushort ov[4];
      ushort4 o;
#pragma unroll
      for (int rr = 0; rr < 4; ++rr) {
        ov[rr] = f2b(acc[fi][fj][rr]);
        float v = b2f(ov[rr]);
        p1[fi][rr] = fmaf(v, a1c, p1[fi][rr]);
        p2[fi][rr] = fmaf(v, a2c, p2[fi][rr]);
      }
      o.x = ov[0]; o.y = ov[1]; o.z = ov[2]; o.w = ov[3];
      *(ushort4*)&WhT[(size_t)col * NV + row0] = o;
    }
  }
#pragma unroll
  for (int fi = 0; fi < 2; ++fi)
#pragma unroll
    for (int rr = 0; rr < 4; ++rr) {
      float s1 = p1[fi][rr], s2 = p2[fi][rr];
#pragma unroll
      for (int m = 1; m < 16; m <<= 1) {
        s1 += __shfl_xor(s1, m);
        s2 += __shfl_xor(s2, m);
      }
      if ((lane & 15) == 0) {
        const int row = i0 + wm * 32 + fi * 16 + ((lane >> 4) << 2) + rr;
        atomicAdd(&f1[row], s1);
        atomicAdd(&f2[row], s2);
      }
    }
}

// ---------------- kernel 2: fused mask/exp/PV partial GEMM, high-occupancy ----------------
// BM=64, BN=256, BK=32, K-split=8; 512 thr (8 waves, 2x4); grid 1024.
// LDS 40 KB + VGPR<=64 (launch_bounds 512,8) -> 4 blk/CU = 32 waves/CU: latency
// hiding via TLP instead of deep register pipelining (R7 showed latency-bound
// at 16 waves/CU with all pipes idle).
__global__ __launch_bounds__(512, 8) void k_gemm2(
    const int* __restrict__ adj, const ushort* __restrict__ WhT,
    const float* __restrict__ f1, const float* __restrict__ f2,
    float* __restrict__ accP, float* __restrict__ Sp) {
  __shared__ __align__(16) ushort Ps[2][64 * 32];     // 8 KB
  __shared__ __align__(16) ushort Bs[2][256 * 32];    // 32 KB

  const int t = threadIdx.x;
  const int lane = t & 63;
  const int w = t >> 6;
  const int wm = w >> 2, wn = w & 3;
  const int bid = blockIdx.x;
  const int ks = bid & (KS - 1);
  const int rb = bid >> 3;
  const int i0 = rb * 64;
  const int jbase = ks * (NV / KS);                    // 1024-col split
  const int NT = (NV / KS) / 32;                       // 32 k-tiles of 32

  const int pr = t >> 3, pq = t & 7;                   // P role: row, 4-col chunk
  const float f1r = f1[i0 + pr];

  // Bs staging: per wave 2 groups of 16 rows; 4 chunks/row, XOR-4 swizzle via source
  const int lrow = lane >> 2;                          // 0..15
  const int lchunk = (lane & 3) ^ (lrow & 3);
  const ushort* wsrc0 = WhT + (size_t)(w * 32 + lrow) * NV + jbase + lchunk * 8;
  const int* adjp = adj + (size_t)(i0 + pr) * NV + jbase + pq * 4;
  const float* f2p = f2 + jbase + pq * 4;
  const int koff = ((lane >> 4) ^ (lane & 3)) * 8;     // swizzled k-chunk (r&3 == lane&3)

  float ssum = 0.f;
  f32x4 acc[2][4] = {};
  int av[4]; float fz[4];

  auto adjload = [&](int tile) {
    int4 a0 = *(const int4*)(adjp + tile * 32);
    av[0] = a0.x; av[1] = a0.y; av[2] = a0.z; av[3] = a0.w;
  };
  auto fzload = [&](int tile) {
    float4 z0 = *(const float4*)(f2p + tile * 32);
    fz[0] = z0.x; fz[1] = z0.y; fz[2] = z0.z; fz[3] = z0.w;
  };
  auto glB = [&](int tile, int buf) {
#pragma unroll
    for (int q = 0; q < 2; ++q)
      gl_lds16(wsrc0 + (size_t)q * 16 * NV + tile * 32, &Bs[buf][w * 1024 + q * 512]);
  };
  auto finish = [&](int buf) {
    ushort ub[4];
#pragma unroll
    for (int e = 0; e < 4; ++e) {
      float x = f1r + fz[e];
      float ee = fminf(fmaxf(x, ALPHA_LRELU * x), 75.f);   // lrelu + overflow guard
      float wv = (av[e] > 0) ? __expf(ee) : 0.f;
      ub[e] = f2b(wv);
      ssum += b2f(ub[e]);
    }
    uint2 pk;
    pk.x = (uint32_t)ub[0] | ((uint32_t)ub[1] << 16);
    pk.y = (uint32_t)ub[2] | ((uint32_t)ub[3] << 16);
    const int off = pr * 32 + (((pq >> 1) ^ (pr & 3)) & 3) * 8 + (pq & 1) * 4;
    *(uint2*)&Ps[buf][off] = pk;
  };
  auto mfma_step = [&](int buf) {
    bf16x8 af[2], bfv[4];
#pragma unroll
    for (int fi = 0; fi < 2; ++fi)
      af[fi] = *(const bf16x8*)&Ps[buf][(wm * 32 + fi * 16 + (lane & 15)) * 32 + koff];
#pragma unroll
    for (int fj = 0; fj < 4; ++fj)
      bfv[fj] = *(const bf16x8*)&Bs[buf][(wn * 64 + fj * 16 + (lane & 15)) * 32 + koff];
#pragma unroll
    for (int fi = 0; fi < 2; ++fi)
#pragma unroll
      for (int fj = 0; fj < 4; ++fj)
        acc[fi][fj] = __builtin_amdgcn_mfma_f32_16x16x32_bf16(af[fi], bfv[fj], acc[fi][fj], 0, 0, 0);
  };

  // ---- prologue: tile 0 ----
  adjload(0); fzload(0);
  glB(0, 0);
  finish(0);
  __syncthreads();

  // ---- main loop ----
  for (int p = 0; p + 1 < NT; ++p) {
    adjload(p + 1); fzload(p + 1);
    glB(p + 1, (p + 1) & 1);
    SBAR0();
    mfma_step(p & 1);                  // covers next-tile load latency
    finish((p + 1) & 1);
    __syncthreads();
  }
  mfma_step((NT - 1) & 1);

  // denom partial: reduce over the 8 chunk-lanes of each row
  ssum += __shfl_xor(ssum, 1);
  ssum += __shfl_xor(ssum, 2);
  ssum += __shfl_xor(ssum, 4);
  if (pq == 0) Sp[(size_t)ks * NV + i0 + pr] = ssum;

  float* ab = accP + (size_t)ks * NV * FOUT;
#pragma unroll
  for (int fi = 0; fi < 2; ++fi) {
    const int ig = i0 + wm * 32 + fi * 16 + ((lane >> 4) << 2);
#pragma unroll
    for (int fj = 0; fj < 4; ++fj) {
      const int col = wn * 64 + fj * 16 + (lane & 15);
#pragma unroll
      for (int rr = 0; rr < 4; ++rr)
        ab[(size_t)(ig + rr) * FOUT + col] = acc[fi][fj][rr];
    }
  }
}

// ---------------- kernel 3: combine 8 partials, divide, ELU, f32 out ----------------
__global__ void k_combine(const float* __restrict__ accP, const float* __restrict__ Sp,
                          float* __restrict__ out) {
  const size_t NF = (size_t)NV * FOUT;
  int g = blockIdx.x * 256 + threadIdx.x;
  int i = g >> 6;
  float4 vs = {0.f, 0.f, 0.f, 0.f};
  float s = 0.f;
#pragma unroll
  for (int p = 0; p < KS; ++p) {
    float4 v = ((const float4*)(accP + (size_t)p * NF))[g];
    vs.x += v.x; vs.y += v.y; vs.z += v.z; vs.w += v.w;
    s += Sp[(size_t)p * NV + i];
  }
  float inv = (s != 0.f) ? (1.0f / s) : 0.f;
  float xs0 = vs.x * inv, xs1 = vs.y * inv, xs2 = vs.z * inv, xs3 = vs.w * inv;
  float4 o;
  o.x = xs0 > 0.f ? xs0 : expm1f(xs0);
  o.y = xs1 > 0.f ? xs1 : expm1f(xs1);
  o.z = xs2 > 0.f ? xs2 : expm1f(xs2);
  o.w = xs3 > 0.f ? xs3 : expm1f(xs3);
  ((float4*)out)[g] = o;
}

extern "C" void kernel_launch(void* const* d_in, const int* in_sizes, int n_in,
                              void* d_out, int out_size, void* d_ws, size_t ws_size,
                              hipStream_t stream) {
  const float* h   = (const float*)d_in[0];        // f32 [8192][512]
  const int*   adj = (const int*)d_in[1];          // int32 [8192][8192]
  const float* W   = (const float*)d_in[2];        // f32 [512][256]
  const float* a   = (const float*)d_in[3];        // f32 [512]
  float* out = (float*)d_out;                      // f32 [8192][256]

  char* ws = (char*)d_ws;
  ushort* WT   = (ushort*)ws;                                   // 256 KB
  ushort* WhT  = (ushort*)(ws + (256ull << 10));                // 4 MB
  float*  f1   = (float*)(ws + (256ull << 10) + (4ull << 20));  // f1,f2 contiguous
  float*  f2   = f1 + NV;
  float*  Sp   = f2 + NV;                                       // 8*8192 floats
  float*  accP = Sp + (size_t)KS * NV;                          // 64 MB

  k_prep_w<<<(FIN * FOUT) / 256, 256, 0, stream>>>(W, WT, f1);
  k_gemm1<<<dim3(NV / 64, FOUT / 64), 256, 0, stream>>>(h, WT, a, WhT, f1, f2);
  k_gemm2<<<(NV / 64) * KS, 512, 0, stream>>>(adj, WhT, f1, f2, accP, Sp);
  k_combine<<<(NV * FOUT / 4) / 256, 256, 0, stream>>>(accP, Sp, out);
}

// Round 11
// 418.446 us; speedup vs baseline: 1.2308x; 1.2308x over previous
//
#include <hip/hip_runtime.h>
#include <hip/hip_bf16.h>
#include <cstdint>

#define NV 8192
#define FIN 512
#define FOUT 256
#define KS 4
#define ALPHA_LRELU 0.2f

using bf16x8 = __attribute__((ext_vector_type(8))) short;
using f32x4  = __attribute__((ext_vector_type(4))) float;

static __device__ __forceinline__ float b2f(ushort u) {
  union { uint32_t u32; float f; } v; v.u32 = ((uint32_t)u) << 16; return v.f;
}
static __device__ __forceinline__ ushort f2b(float f) {
  union { float f; uint32_t u; } v; v.f = f;
  uint32_t r = (v.u + 0x7fffu + ((v.u >> 16) & 1u)) >> 16;
  return (ushort)r;
}
static __device__ __forceinline__ uint32_t pk2(float a, float b) {
  return (uint32_t)f2b(a) | ((uint32_t)f2b(b) << 16);
}
// swizzled element index of an 8-elem (16B) chunk; tile row stride 64 elems (128B)
static __device__ __forceinline__ int swz(int row, int kchunk) {
  return (row << 6) + (((kchunk ^ (row & 7)) & 7) << 3);
}
// direct global->LDS, 16B per lane (dest = wave-uniform base + lane*16)
static __device__ __forceinline__ void gl_lds16(const ushort* g, ushort* l) {
  __builtin_amdgcn_global_load_lds(
      (const __attribute__((address_space(1))) uint32_t*)(uintptr_t)g,
      (__attribute__((address_space(3))) uint32_t*)(uint32_t)(uintptr_t)l,
      16, 0, 0);
}

// ---------------- prep: W f32 -> WT bf16 (transposed) + zero f1/f2 ----------------
__global__ void k_prep_w(const float* __restrict__ W, ushort* __restrict__ WT,
                         float* __restrict__ f1z) {
  int t = blockIdx.x * 256 + threadIdx.x;
  int n = t >> 9, k = t & 511;
  WT[(size_t)n * FIN + k] = f2b(W[(size_t)k * FOUT + n]);
  if (t < 2 * NV) f1z[t] = 0.f;          // f1 and f2 are contiguous
}

// ---------------- kernel 1: WhT[c][i] = (h@W)^T bf16, + f1/f2 partials ----------------
__global__ __launch_bounds__(256, 4) void k_gemm1(
    const float* __restrict__ h, const ushort* __restrict__ WT,
    const float* __restrict__ a,
    ushort* __restrict__ WhT, float* __restrict__ f1, float* __restrict__ f2) {
  __shared__ __align__(16) ushort As[64 * 64];
  __shared__ __align__(16) ushort Ws[64 * 64];
  const int t = threadIdx.x;
  const int lane = t & 63;
  const int w = t >> 6;
  const int wm = w >> 1, wn = w & 1;
  const int i0 = blockIdx.x * 64;
  const int n0 = blockIdx.y * 64;

  f32x4 acc[2][2] = {};
  const int srow = t & 63, sseg = t >> 6;

  for (int kt = 0; kt < FIN / 64; ++kt) {
    const int k0 = kt * 64;
    {
      const float4* gA = (const float4*)(h + (size_t)(i0 + srow) * FIN + k0 + sseg * 16);
      float4 v0 = gA[0], v1 = gA[1], v2 = gA[2], v3 = gA[3];
      uint4 c0, c1;
      c0.x = pk2(v0.x, v0.y); c0.y = pk2(v0.z, v0.w);
      c0.z = pk2(v1.x, v1.y); c0.w = pk2(v1.z, v1.w);
      c1.x = pk2(v2.x, v2.y); c1.y = pk2(v2.z, v2.w);
      c1.z = pk2(v3.x, v3.y); c1.w = pk2(v3.z, v3.w);
      *(uint4*)&As[swz(srow, sseg * 2 + 0)] = c0;
      *(uint4*)&As[swz(srow, sseg * 2 + 1)] = c1;
    }
    {
      const uint4* gB = (const uint4*)(WT + (size_t)(n0 + srow) * FIN + k0 + sseg * 16);
      uint4 b0 = gB[0], b1 = gB[1];
      *(uint4*)&Ws[swz(srow, sseg * 2 + 0)] = b0;
      *(uint4*)&Ws[swz(srow, sseg * 2 + 1)] = b1;
    }
    __syncthreads();
#pragma unroll
    for (int kk = 0; kk < 2; ++kk) {
      const int kc = kk * 4 + (lane >> 4);
      bf16x8 af[2], bfv[2];
#pragma unroll
      for (int fi = 0; fi < 2; ++fi)
        af[fi] = *(const bf16x8*)&As[swz(wm * 32 + fi * 16 + (lane & 15), kc)];
#pragma unroll
      for (int fj = 0; fj < 2; ++fj)
        bfv[fj] = *(const bf16x8*)&Ws[swz(wn * 32 + fj * 16 + (lane & 15), kc)];
#pragma unroll
      for (int fi = 0; fi < 2; ++fi)
#pragma unroll
        for (int fj = 0; fj < 2; ++fj)
          acc[fi][fj] = __builtin_amdgcn_mfma_f32_16x16x32_bf16(af[fi], bfv[fj], acc[fi][fj], 0, 0, 0);
    }
    __syncthreads();
  }

  float p1[2][4] = {}, p2[2][4] = {};
#pragma unroll
  for (int fi = 0; fi < 2; ++fi) {
    const int row0 = i0 + wm * 32 + fi * 16 + ((lane >> 4) << 2);
#pragma unroll
    for (int fj = 0; fj < 2; ++fj) {
      const int col = n0 + wn * 32 + fj * 16 + (lane & 15);
      const float a1c = a[col], a2c = a[FOUT + col];
      ushort ov[4];
      ushort4 o;
#pragma unroll
      for (int rr = 0; rr < 4; ++rr) {
        ov[rr] = f2b(acc[fi][fj][rr]);
        float v = b2f(ov[rr]);
        p1[fi][rr] = fmaf(v, a1c, p1[fi][rr]);
        p2[fi][rr] = fmaf(v, a2c, p2[fi][rr]);
      }
      o.x = ov[0]; o.y = ov[1]; o.z = ov[2]; o.w = ov[3];
      *(ushort4*)&WhT[(size_t)col * NV + row0] = o;
    }
  }
#pragma unroll
  for (int fi = 0; fi < 2; ++fi)
#pragma unroll
    for (int rr = 0; rr < 4; ++rr) {
      float s1 = p1[fi][rr], s2 = p2[fi][rr];
#pragma unroll
      for (int m = 1; m < 16; m <<= 1) {
        s1 += __shfl_xor(s1, m);
        s2 += __shfl_xor(s2, m);
      }
      if ((lane & 15) == 0) {
        const int row = i0 + wm * 32 + fi * 16 + ((lane >> 4) << 2) + rr;
        atomicAdd(&f1[row], s1);
        atomicAdd(&f2[row], s2);
      }
    }
}

// ---------------- kernel 2: fused mask/exp/PV partial GEMM ----------------
// BM=64, BN=256 (full), K-split=4; 512 thr (8 waves, 2x4); grid 512 (2 blk/CU)
// adj/f2: 2-phase-deep named register sets; Bs/Ps double-buffered;
// all of a phase's loads issue before its MFMA cluster; one __syncthreads/phase.
__global__ __launch_bounds__(512, 4) void k_gemm2(
    const int* __restrict__ adj, const ushort* __restrict__ WhT,
    const float* __restrict__ f1, const float* __restrict__ f2,
    float* __restrict__ accP, float* __restrict__ Sp) {
  __shared__ __align__(16) ushort Ps[2][64 * 64];     // 16 KB
  __shared__ __align__(16) ushort Bs[2][256 * 64];    // 64 KB  (80 KB -> 2 blk/CU)

  const int t = threadIdx.x;
  const int lane = t & 63;
  const int w = t >> 6;
  const int wm = w >> 2, wn = w & 3;
  const int bid = blockIdx.x;
  const int ks = bid & (KS - 1);
  const int rb = bid >> 2;
  const int i0 = rb * 64;
  const int jbase = ks * (NV / KS);
  const int NT = (NV / KS) / 64;                       // 32 k-tiles

  const int pr = t >> 3, pq = t & 7;                   // P role: row, 8-col chunk
  const float f1r = f1[i0 + pr];

  const int lrow = lane >> 3;
  const int lchunk = (lane & 7) ^ lrow;                // pre-swizzled source chunk
  const ushort* wsrc0 = WhT + (size_t)(w * 32 + lrow) * NV + jbase + lchunk * 8;
  const int* adjp = adj + (size_t)(i0 + pr) * NV + jbase + pq * 8;
  const float* f2p = f2 + jbase + pq * 8;

  float ssum = 0.f;
  f32x4 acc[2][4] = {};
  int avA[8], avB[8];
  float fzA[8], fzB[8];

  auto adjload = [&](int tile, int (&av)[8]) {
    int4 a0 = *(const int4*)(adjp + tile * 64);
    int4 a1 = *(const int4*)(adjp + tile * 64 + 4);
    av[0] = a0.x; av[1] = a0.y; av[2] = a0.z; av[3] = a0.w;
    av[4] = a1.x; av[5] = a1.y; av[6] = a1.z; av[7] = a1.w;
  };
  auto fzload = [&](int tile, float (&fz)[8]) {
    float4 z0 = *(const float4*)(f2p + tile * 64);
    float4 z1 = *(const float4*)(f2p + tile * 64 + 4);
    fz[0] = z0.x; fz[1] = z0.y; fz[2] = z0.z; fz[3] = z0.w;
    fz[4] = z1.x; fz[5] = z1.y; fz[6] = z1.z; fz[7] = z1.w;
  };
  auto glB = [&](int tile, int buf) {
    const int koff = tile * 64;
#pragma unroll
    for (int q = 0; q < 4; ++q)
      gl_lds16(wsrc0 + (size_t)q * 8 * NV + koff, &Bs[buf][(w * 4 + q) * 512]);
  };
  auto finish = [&](const int (&av)[8], const float (&fz)[8], int buf) {
    ushort ub[8];
#pragma unroll
    for (int e = 0; e < 8; ++e) {
      float x = f1r + fz[e];
      float ee = fminf(fmaxf(x, ALPHA_LRELU * x), 75.f);   // lrelu + overflow guard
      float wv = (av[e] > 0) ? __expf(ee) : 0.f;
      ub[e] = f2b(wv);
      ssum += b2f(ub[e]);
    }
    uint4 pk;
    pk.x = (uint32_t)ub[0] | ((uint32_t)ub[1] << 16);
    pk.y = (uint32_t)ub[2] | ((uint32_t)ub[3] << 16);
    pk.z = (uint32_t)ub[4] | ((uint32_t)ub[5] << 16);
    pk.w = (uint32_t)ub[6] | ((uint32_t)ub[7] << 16);
    *(uint4*)&Ps[buf][swz(pr, pq)] = pk;
  };
  auto mfma_step = [&](int buf) {
#pragma unroll
    for (int kk = 0; kk < 2; ++kk) {
      const int kc = kk * 4 + (lane >> 4);
      bf16x8 af[2], bfv[4];
#pragma unroll
      for (int fi = 0; fi < 2; ++fi)
        af[fi] = *(const bf16x8*)&Ps[buf][swz(wm * 32 + fi * 16 + (lane & 15), kc)];
#pragma unroll
      for (int fj = 0; fj < 4; ++fj)
        bfv[fj] = *(const bf16x8*)&Bs[buf][swz(wn * 64 + fj * 16 + (lane & 15), kc)];
#pragma unroll
      for (int fi = 0; fi < 2; ++fi)
#pragma unroll
        for (int fj = 0; fj < 4; ++fj)
          acc[fi][fj] = __builtin_amdgcn_mfma_f32_16x16x32_bf16(af[fi], bfv[fj], acc[fi][fj], 0, 0, 0);
    }
  };

  // ---- prologue: tile0 staged; tile1 adj/f2 in named regs ----
  adjload(0, avA); fzload(0, fzA);
  glB(0, 0);
  adjload(1, avB); fzload(1, fzB);
  finish(avA, fzA, 0);                  // waits only on set A
  __syncthreads();

  // ---- main loop: two phases per iteration; kt = 0,2,..,NT-4 ----
  for (int kt = 0; kt + 2 < NT; kt += 2) {
    // even phase (cur=0): loads first, then compute; finish uses LAST phase's set B
    glB(kt + 1, 1);
    adjload(kt + 2, avA); fzload(kt + 2, fzA);
    mfma_step(0);
    finish(avB, fzB, 1);
    __syncthreads();
    // odd phase (cur=1)
    glB(kt + 2, 0);
    adjload(kt + 3, avB); fzload(kt + 3, fzB);
    mfma_step(1);
    finish(avA, fzA, 0);
    __syncthreads();
  }

  // ---- tail: phase NT-2 (cur=0) ----
  glB(NT - 1, 1);
  mfma_step(0);
  finish(avB, fzB, 1);
  __syncthreads();
  // ---- tail: phase NT-1 (cur=1), compute only ----
  mfma_step(1);

  // denom partial: reduce over the 8 chunk-lanes of each row
  ssum += __shfl_xor(ssum, 1);
  ssum += __shfl_xor(ssum, 2);
  ssum += __shfl_xor(ssum, 4);
  if (pq == 0) Sp[(size_t)ks * NV + i0 + pr] = ssum;

  float* ab = accP + (size_t)ks * NV * FOUT;
#pragma unroll
  for (int fi = 0; fi < 2; ++fi) {
    const int ig = i0 + wm * 32 + fi * 16 + ((lane >> 4) << 2);
#pragma unroll
    for (int fj = 0; fj < 4; ++fj) {
      const int col = wn * 64 + fj * 16 + (lane & 15);
#pragma unroll
      for (int rr = 0; rr < 4; ++rr)
        ab[(size_t)(ig + rr) * FOUT + col] = acc[fi][fj][rr];
    }
  }
}

// ---------------- kernel 3: combine partials, divide, ELU, f32 out ----------------
__global__ void k_combine(const float* __restrict__ accP, const float* __restrict__ Sp,
                          float* __restrict__ out) {
  const size_t NF = (size_t)NV * FOUT;
  int g = blockIdx.x * 256 + threadIdx.x;
  int i = g >> 6;
  float4 v0 = ((const float4*)accP)[g];
  float4 v1 = ((const float4*)(accP + NF))[g];
  float4 v2 = ((const float4*)(accP + 2 * NF))[g];
  float4 v3 = ((const float4*)(accP + 3 * NF))[g];
  float s = Sp[i] + Sp[NV + i] + Sp[2 * NV + i] + Sp[3 * NV + i];
  float inv = (s != 0.f) ? (1.0f / s) : 0.f;
  float xs0 = (v0.x + v1.x + v2.x + v3.x) * inv;
  float xs1 = (v0.y + v1.y + v2.y + v3.y) * inv;
  float xs2 = (v0.z + v1.z + v2.z + v3.z) * inv;
  float xs3 = (v0.w + v1.w + v2.w + v3.w) * inv;
  float4 o;
  o.x = xs0 > 0.f ? xs0 : expm1f(xs0);
  o.y = xs1 > 0.f ? xs1 : expm1f(xs1);
  o.z = xs2 > 0.f ? xs2 : expm1f(xs2);
  o.w = xs3 > 0.f ? xs3 : expm1f(xs3);
  ((float4*)out)[g] = o;
}

extern "C" void kernel_launch(void* const* d_in, const int* in_sizes, int n_in,
                              void* d_out, int out_size, void* d_ws, size_t ws_size,
                              hipStream_t stream) {
  const float* h   = (const float*)d_in[0];        // f32 [8192][512]
  const int*   adj = (const int*)d_in[1];          // int32 [8192][8192]
  const float* W   = (const float*)d_in[2];        // f32 [512][256]
  const float* a   = (const float*)d_in[3];        // f32 [512]
  float* out = (float*)d_out;                      // f32 [8192][256]

  char* ws = (char*)d_ws;
  ushort* WT   = (ushort*)ws;                                   // 256 KB
  ushort* WhT  = (ushort*)(ws + (256ull << 10));                // 4 MB
  float*  f1   = (float*)(ws + (256ull << 10) + (4ull << 20));  // f1,f2 contiguous
  float*  f2   = f1 + NV;
  float*  Sp   = f2 + NV;                                       // 4*8192 floats
  float*  accP = Sp + (size_t)KS * NV;                          // 32 MB

  k_prep_w<<<(FIN * FOUT) / 256, 256, 0, stream>>>(W, WT, f1);
  k_gemm1<<<dim3(NV / 64, FOUT / 64), 256, 0, stream>>>(h, WT, a, WhT, f1, f2);
  k_gemm2<<<(NV / 64) * KS, 512, 0, stream>>>(adj, WhT, f1, f2, accP, Sp);
  k_combine<<<(NV * FOUT / 4) / 256, 256, 0, stream>>>(accP, Sp, out);
}